// Round 5
// baseline (329.119 us; speedup 1.0000x reference)
//
#include <hip/hip_runtime.h>
#include <math.h>

#define SEQL 4096
#define L2E 1.44269504088896340736f

#if defined(__has_builtin)
#if __has_builtin(__builtin_amdgcn_exp2f)
#define FAST_EXP2(x) __builtin_amdgcn_exp2f(x)
#endif
#endif
#ifndef FAST_EXP2
#define FAST_EXP2(x) exp2f(x)
#endif

__device__ __forceinline__ float sigmoid_f(float x){ return 1.0f/(1.0f+expf(-x)); }

// ---------------- conv 3x3, pad 1, 64x64 image ----------------
// No LDS, no shuffles, no barriers. lane=w; ty=row in 4-row tile; COG output
// channels per thread. Inputs via global loads (vmcnt, L1/L2-hit), weights via
// scalar loads (sole lgkm users -> compiler prefetches across ci).
template<int CI, int CO, int COG, bool RELU, bool RES>
__global__ __launch_bounds__(256,4) void conv3x3_k(const float* __restrict__ in,
    const float* __restrict__ wgt, const float* __restrict__ bias,
    const float* __restrict__ res, float* __restrict__ out)
{
  const int lane = threadIdx.x & 63;            // w
  const int ty   = threadIdx.x >> 6;            // 0..3 (wave id)
  const int h    = blockIdx.x*4 + ty;           // output row (wave-uniform)
  const int co0  = blockIdx.y*COG;
  const int b    = blockIdx.z;
  const int wl = (lane==0)  ? 0  : lane-1;      // clamped (stay in-bounds)
  const int wr = (lane==63) ? 63 : lane+1;
  float acc[COG];
  #pragma unroll
  for (int u=0;u<COG;++u) acc[u] = bias[co0+u];

  #pragma unroll 2
  for (int ci=0; ci<CI; ++ci){
    const float* p = in + ((size_t)(b*CI+ci))*4096;
    float L[3], M[3], R[3];
    #pragma unroll
    for (int j=0;j<3;++j){
      int hh = h - 1 + j;                       // wave-uniform bounds branch
      if (hh>=0 && hh<64){
        const float* row = p + hh*64;
        float lv = row[wl], mv = row[lane], rv = row[wr];
        if (lane==0)  lv = 0.0f;
        if (lane==63) rv = 0.0f;
        L[j]=lv; M[j]=mv; R[j]=rv;
      } else { L[j]=0.0f; M[j]=0.0f; R[j]=0.0f; }
    }
    #pragma unroll
    for (int u=0;u<COG;++u){
      const float* wp = wgt + ((size_t)(co0+u)*CI + ci)*9;   // uniform -> s_load
      #pragma unroll
      for (int j=0;j<3;++j){
        acc[u] = fmaf(L[j], wp[j*3+0], acc[u]);
        acc[u] = fmaf(M[j], wp[j*3+1], acc[u]);
        acc[u] = fmaf(R[j], wp[j*3+2], acc[u]);
      }
    }
  }
  #pragma unroll
  for (int u=0;u<COG;++u){
    size_t ob = ((size_t)(b*CO+co0+u))*4096 + (size_t)h*64 + lane;
    float v = acc[u];
    if constexpr (RES)  v += res[ob];
    if constexpr (RELU) v = fmaxf(v, 0.0f);
    out[ob] = v;
  }
}

// ---------------- LayerNorm(32) + in_proj (32->128) + silu on z half --------
__global__ __launch_bounds__(512) void ln_inproj_k(const float* __restrict__ x2,
    const float* __restrict__ g, const float* __restrict__ be,
    const float* __restrict__ Wip, float* __restrict__ xm_pre, float* __restrict__ sz)
{
  __shared__ float xn[64][36];
  const int tid = threadIdx.x, lane = tid & 63, ty = tid >> 6;
  const int bi = blockIdx.x >> 6;
  const int l0 = (blockIdx.x & 63) << 6;
  if (ty == 0){
    const float* row = x2 + (size_t)bi*131072 + (size_t)(l0+lane)*32;
    float v[32];
    #pragma unroll
    for (int c=0;c<32;c+=4){
      float4 f = *(const float4*)(row + c);
      v[c]=f.x; v[c+1]=f.y; v[c+2]=f.z; v[c+3]=f.w;
    }
    float p[8];
    #pragma unroll
    for (int j2=0;j2<8;++j2) p[j2]=v[j2];
    #pragma unroll
    for (int i=8;i<32;i+=8){
      #pragma unroll
      for (int j2=0;j2<8;++j2) p[j2]+=v[i+j2];
    }
    float mu = (((p[0]+p[1])+(p[2]+p[3]))+((p[4]+p[5])+(p[6]+p[7]))) * 0.03125f;
    float q[8];
    #pragma unroll
    for (int j2=0;j2<8;++j2){ float dd=v[j2]-mu; q[j2]=dd*dd; }
    #pragma unroll
    for (int i=8;i<32;i+=8){
      #pragma unroll
      for (int j2=0;j2<8;++j2){ float dd=v[i+j2]-mu; q[j2]+=dd*dd; }
    }
    float var = (((q[0]+q[1])+(q[2]+q[3]))+((q[4]+q[5])+(q[6]+q[7]))) * 0.03125f;
    float rstd = 1.0f / sqrtf(var + 1e-5f);
    #pragma unroll
    for (int c=0;c<32;++c) xn[lane][c] = (v[c]-mu)*rstd*g[c] + be[c];
  }
  __syncthreads();
  float xv[32];
  #pragma unroll
  for (int c=0;c<32;c+=4){
    float4 f = *(const float4*)(&xn[lane][c]);
    xv[c]=f.x; xv[c+1]=f.y; xv[c+2]=f.z; xv[c+3]=f.w;
  }
  #pragma unroll
  for (int jj=0;jj<16;++jj){
    int j = (ty<<4) + jj;
    const float* wr = Wip + j*32;
    float acc = 0.0f;
    #pragma unroll
    for (int c=0;c<32;++c) acc = fmaf(xv[c], wr[c], acc);
    size_t o = ((size_t)(bi*64 + (j & 63)))*SEQL + l0 + lane;
    if (j < 64) xm_pre[o] = acc;
    else        sz[o] = acc * sigmoid_f(acc);
  }
}

// ---- fused: depthwise causal conv1d+silu, x_proj (64->66), dt_proj+softplus, B/C split
__global__ __launch_bounds__(512) void xproj_k(const float* __restrict__ xm_pre,
    const float* __restrict__ cw, const float* __restrict__ cb,
    const float* __restrict__ Wxp, const float* __restrict__ Wdt,
    const float* __restrict__ bdt, float* __restrict__ xm2,
    float* __restrict__ delta, float* __restrict__ Bm, float* __restrict__ Cm)
{
  __shared__ float xs[64][68];   // xs[d][c] = xm_pre[l0-3+c], c in 0..66
  __shared__ float xt[64][68];   // xt[l][d] = silu(conv) transposed
  __shared__ float xd[64][68];   // xd[l][j], j in 0..65
  const int tid = threadIdx.x, lane = tid & 63, ty = tid >> 6;
  const int bi = blockIdx.x >> 6;
  const int l0 = (blockIdx.x & 63) << 6;
  for (int r=ty; r<64; r+=8){
    const float* src = xm_pre + ((size_t)(bi*64+r))*SEQL + l0;
    float v = 0.0f;
    if (l0 + lane - 3 >= 0) v = src[lane-3];
    xs[r][lane] = v;
    if (lane < 3) xs[r][64+lane] = src[61+lane];
  }
  __syncthreads();
  for (int r=ty; r<64; r+=8){
    float w0=cw[r*4], w1=cw[r*4+1], w2=cw[r*4+2], w3=cw[r*4+3], bv=cb[r];
    float a = xs[r][lane]*w0 + xs[r][lane+1]*w1 + xs[r][lane+2]*w2 + xs[r][lane+3]*w3 + bv;
    float s = a * sigmoid_f(a);
    xt[lane][r] = s;
    xm2[((size_t)(bi*64+r))*SEQL + l0 + lane] = s;
  }
  __syncthreads();
  float xv[64];
  #pragma unroll
  for (int c=0;c<64;c+=4){
    float4 f = *(const float4*)(&xt[lane][c]);
    xv[c]=f.x; xv[c+1]=f.y; xv[c+2]=f.z; xv[c+3]=f.w;
  }
  for (int j=ty; j<66; j+=8){
    const float* wr = Wxp + j*64;
    float acc = 0.0f;
    #pragma unroll
    for (int c=0;c<64;++c) acc = fmaf(xv[c], wr[c], acc);
    xd[lane][j] = acc;
  }
  __syncthreads();
  float dt0 = xd[lane][0], dt1 = xd[lane][1];
  #pragma unroll
  for (int k=0;k<8;++k){
    int d2 = ty*8 + k;
    float v = dt0*Wdt[d2*2] + dt1*Wdt[d2*2+1] + bdt[d2];
    float sp = fmaxf(v,0.0f) + log1pf(expf(-fabsf(v)));
    delta[((size_t)(bi*64+d2))*SEQL + l0 + lane] = sp;
  }
  const int which = ty >> 2, gq = ty & 3;
  float* dst = which ? Cm : Bm;
  size_t base = ((size_t)bi*SEQL + l0 + lane)*32 + gq*8;
  const int s0 = 2 + which*32 + gq*8;
  float4 f0, f1;
  f0.x = xd[lane][s0+0]; f0.y = xd[lane][s0+1]; f0.z = xd[lane][s0+2]; f0.w = xd[lane][s0+3];
  f1.x = xd[lane][s0+4]; f1.y = xd[lane][s0+5]; f1.z = xd[lane][s0+6]; f1.w = xd[lane][s0+7];
  *(float4*)(dst + base)     = f0;
  *(float4*)(dst + base + 4) = f1;
}

// ---------------- selective scan: 3-kernel chunked scan, chunk=64 ----------
__global__ __launch_bounds__(256) void scan_p1(const float* __restrict__ dlt,
    const float* __restrict__ xssm, const float* __restrict__ Bm,
    const float* __restrict__ A_log, float* __restrict__ cA, float* __restrict__ cH)
{
  const int tid = threadIdx.x;
  const int n = tid & 31;
  const int chunk = (blockIdx.x & 7)*8 + (tid >> 5);
  const int bd = blockIdx.x >> 3;
  const int b = bd >> 6, d = bd & 63;
  const int l0 = chunk << 6;
  const float Av2 = -expf(A_log[d*32+n]) * L2E;
  const float* del = dlt  + (size_t)bd*SEQL + l0;
  const float* xp  = xssm + (size_t)bd*SEQL + l0;
  const float* Bp  = Bm + ((size_t)b*SEQL + l0)*32 + n;
  float h = 0.0f, aP = 1.0f;
  #pragma unroll 4
  for (int i0=0;i0<64;i0+=4){
    float4 d4 = *(const float4*)(del+i0);
    float4 x4 = *(const float4*)(xp +i0);
    float b0 = Bp[(i0+0)*32], b1 = Bp[(i0+1)*32], b2 = Bp[(i0+2)*32], b3 = Bp[(i0+3)*32];
    float a0 = FAST_EXP2(d4.x*Av2); h = fmaf(a0,h, d4.x*b0*x4.x); aP *= a0;
    float a1 = FAST_EXP2(d4.y*Av2); h = fmaf(a1,h, d4.y*b1*x4.y); aP *= a1;
    float a2 = FAST_EXP2(d4.z*Av2); h = fmaf(a2,h, d4.z*b2*x4.z); aP *= a2;
    float a3 = FAST_EXP2(d4.w*Av2); h = fmaf(a3,h, d4.w*b3*x4.w); aP *= a3;
  }
  int idx = (bd*64+chunk)*32 + n;
  cA[idx] = aP; cH[idx] = h;
}

__global__ __launch_bounds__(128) void scan_comb(const float* __restrict__ cA,
    float* __restrict__ cH)
{
  const int gid = blockIdx.x*128 + threadIdx.x;   // 8192 = 256 bd x 32 n
  const int n = gid & 31, bd = gid >> 5;
  const size_t base = (size_t)bd*64*32 + n;
  float hrun = 0.0f;
  #pragma unroll 8
  for (int c=0;c<64;++c){
    float ac = cA[base + c*32];
    float hc = cH[base + c*32];
    cH[base + c*32] = hrun;                        // exclusive prefix
    hrun = fmaf(ac, hrun, hc);
  }
}

__global__ __launch_bounds__(256) void scan_p2(const float* __restrict__ dlt,
    const float* __restrict__ xssm, const float* __restrict__ Bm,
    const float* __restrict__ Cm, const float* __restrict__ A_log,
    const float* __restrict__ Dp, const float* __restrict__ sz,
    const float* __restrict__ cH, float* __restrict__ yt)
{
  const int tid = threadIdx.x;
  const int n = tid & 31;
  const int chunk = (blockIdx.x & 7)*8 + (tid >> 5);
  const int bd = blockIdx.x >> 3;
  const int b = bd >> 6, d = bd & 63;
  const int l0 = chunk << 6;
  const float Av2 = -expf(A_log[d*32+n]) * L2E;
  const float Dv = Dp[d];
  const float* del = dlt  + (size_t)bd*SEQL + l0;
  const float* xp  = xssm + (size_t)bd*SEQL + l0;
  const float* szp = sz   + (size_t)bd*SEQL + l0;
  const float* Bp  = Bm + ((size_t)b*SEQL + l0)*32 + n;
  const float* Cp  = Cm + ((size_t)b*SEQL + l0)*32 + n;
  float* yp = yt + (size_t)bd*SEQL + l0;
  float h = cH[(bd*64+chunk)*32 + n];
  #pragma unroll 2
  for (int i0=0;i0<64;i0+=4){
    float4 d4 = *(const float4*)(del+i0);
    float4 x4 = *(const float4*)(xp +i0);
    float4 s4 = *(const float4*)(szp+i0);
    float b0 = Bp[(i0+0)*32], b1 = Bp[(i0+1)*32], b2 = Bp[(i0+2)*32], b3 = Bp[(i0+3)*32];
    float c0 = Cp[(i0+0)*32], c1 = Cp[(i0+1)*32], c2 = Cp[(i0+2)*32], c3 = Cp[(i0+3)*32];
    float a0 = FAST_EXP2(d4.x*Av2); h = fmaf(a0,h, d4.x*b0*x4.x);
    float v0 = h*c0;
    float a1 = FAST_EXP2(d4.y*Av2); h = fmaf(a1,h, d4.y*b1*x4.y);
    float v1 = h*c1;
    float a2 = FAST_EXP2(d4.z*Av2); h = fmaf(a2,h, d4.z*b2*x4.z);
    float v2 = h*c2;
    float a3 = FAST_EXP2(d4.w*Av2); h = fmaf(a3,h, d4.w*b3*x4.w);
    float v3 = h*c3;
    v0 += __shfl_xor(v0,16); v0 += __shfl_xor(v0,8); v0 += __shfl_xor(v0,4);
    v0 += __shfl_xor(v0,2);  v0 += __shfl_xor(v0,1);
    v1 += __shfl_xor(v1,16); v1 += __shfl_xor(v1,8); v1 += __shfl_xor(v1,4);
    v1 += __shfl_xor(v1,2);  v1 += __shfl_xor(v1,1);
    v2 += __shfl_xor(v2,16); v2 += __shfl_xor(v2,8); v2 += __shfl_xor(v2,4);
    v2 += __shfl_xor(v2,2);  v2 += __shfl_xor(v2,1);
    v3 += __shfl_xor(v3,16); v3 += __shfl_xor(v3,8); v3 += __shfl_xor(v3,4);
    v3 += __shfl_xor(v3,2);  v3 += __shfl_xor(v3,1);
    if (n==0){
      yp[i0+0] = fmaf(x4.x, Dv, v0) * s4.x;
      yp[i0+1] = fmaf(x4.y, Dv, v1) * s4.y;
      yp[i0+2] = fmaf(x4.z, Dv, v2) * s4.z;
      yp[i0+3] = fmaf(x4.w, Dv, v3) * s4.w;
    }
  }
}

// ---------------- out_proj (64->32) into (b,c,l) = NCHW image --------------
__global__ __launch_bounds__(512) void outproj_k(const float* __restrict__ yt,
    const float* __restrict__ Wout, float* __restrict__ ym)
{
  __shared__ float ys[64][68];    // ys[l][d]
  const int tid = threadIdx.x, lane = tid & 63, ty = tid >> 6;
  const int bi = blockIdx.x >> 6;
  const int l0 = (blockIdx.x & 63) << 6;
  for (int r=ty; r<64; r+=8)
    ys[lane][r] = yt[((size_t)(bi*64+r))*SEQL + l0 + lane];
  __syncthreads();
  float yv[64];
  #pragma unroll
  for (int c=0;c<64;c+=4){
    float4 f = *(const float4*)(&ys[lane][c]);
    yv[c]=f.x; yv[c+1]=f.y; yv[c+2]=f.z; yv[c+3]=f.w;
  }
  #pragma unroll
  for (int jj=0;jj<4;++jj){
    int j = ty*4 + jj;
    const float* wr = Wout + j*64;
    float acc = 0.0f;
    #pragma unroll
    for (int c=0;c<64;++c) acc = fmaf(yv[c], wr[c], acc);
    ym[((size_t)(bi*32+j))*SEQL + l0 + lane] = acc;
  }
}

extern "C" void kernel_launch(void* const* d_in, const int* in_sizes, int n_in,
                              void* d_out, int out_size, void* d_ws, size_t ws_size,
                              hipStream_t stream) {
  const float* x        = (const float*)d_in[0];
  const float* conv1_w  = (const float*)d_in[1];
  const float* conv1_b  = (const float*)d_in[2];
  const float* conv2_w  = (const float*)d_in[3];
  const float* conv2_b  = (const float*)d_in[4];
  const float* ln_g     = (const float*)d_in[5];
  const float* ln_b     = (const float*)d_in[6];
  const float* in_proj_w= (const float*)d_in[7];
  const float* conv1d_w = (const float*)d_in[8];
  const float* conv1d_b = (const float*)d_in[9];
  const float* x_proj_w = (const float*)d_in[10];
  const float* dt_proj_w= (const float*)d_in[11];
  const float* dt_proj_b= (const float*)d_in[12];
  const float* A_log    = (const float*)d_in[13];
  const float* Dp       = (const float*)d_in[14];
  const float* out_proj_w=(const float*)d_in[15];
  const float* smooth_w = (const float*)d_in[16];
  const float* smooth_b = (const float*)d_in[17];
  float* out = (float*)d_out;

  float* ws = (float*)d_ws;
  float* t      = ws;                 // (4,64,64,64)  1048576  (free after conv2)
  float* x2     = t      + 1048576;   // (4,32,4096)    524288
  float* xm_pre = x2     + 524288;    // (4,64,4096)   1048576
  float* xm2    = xm_pre + 1048576;   // (4,64,4096)   1048576
  float* szb    = xm2    + 1048576;   // (4,64,4096)   1048576
  float* dlt    = szb    + 1048576;   // (4,64,4096)   1048576
  float* Bmat   = dlt    + 1048576;   // (4,4096,32)    524288
  float* Cmat   = Bmat   + 524288;    // (4,4096,32)    524288
  float* yt     = Cmat   + 524288;    // (4,64,4096)   1048576
  float* ym     = yt     + 1048576;   // (4,32,4096)    524288
  float* cA     = t;                  // (256,64,32)    524288 (aliases t)
  float* cH     = t + 524288;         // (256,64,32)    524288 (aliases t)

  // conv1: 32->64, COG=4 -> grid (16,16,4)=1024 blocks (16 waves/CU)
  conv3x3_k<32,64,4,true ,false><<<dim3(16,16,4), 256, 0, stream>>>(x,  conv1_w, conv1_b, nullptr, t);
  // conv2: 64->32 + residual, COG=4 -> grid (16,8,4)=512 blocks
  conv3x3_k<64,32,4,false,true ><<<dim3(16,8,4), 256, 0, stream>>>(t,  conv2_w, conv2_b, x,       x2);
  ln_inproj_k <<<256, 512, 0, stream>>>(x2, ln_g, ln_b, in_proj_w, xm_pre, szb);
  xproj_k     <<<256, 512, 0, stream>>>(xm_pre, conv1d_w, conv1d_b, x_proj_w, dt_proj_w, dt_proj_b,
                                        xm2, dlt, Bmat, Cmat);
  scan_p1     <<<2048, 256, 0, stream>>>(dlt, xm2, Bmat, A_log, cA, cH);
  scan_comb   <<<64,   128, 0, stream>>>(cA, cH);
  scan_p2     <<<2048, 256, 0, stream>>>(dlt, xm2, Bmat, Cmat, A_log, Dp, szb, cH, yt);
  outproj_k   <<<256, 512, 0, stream>>>(yt, out_proj_w, ym);
  // smooth: 32->32, COG=4 -> grid (16,8,4)=512 blocks
  conv3x3_k<32,32,4,false,false><<<dim3(16,8,4), 256, 0, stream>>>(ym, smooth_w, smooth_b, nullptr, out);
}